// Round 2
// baseline (1274.269 us; speedup 1.0000x reference)
//
#include <hip/hip_runtime.h>
#include <hip/hip_bf16.h>

typedef __bf16 bf16_t;
typedef bf16_t bf16x8 __attribute__((ext_vector_type(8)));
typedef float f32x4 __attribute__((ext_vector_type(4)));

#define TOK 8192          // B*S
#define DMODEL 2048
#define DINNER 4096
#define XBCN 4352         // conv dim = 34*128, no pad needed
#define DSTATE 128
#define NH 64
#define HD 64
#define NBC 64            // B * (S/CHUNK) = 2*32
#define WINT_ROWS 8448    // z (4096) + xbc (4352)

// ---------------- utility kernels ----------------

__global__ __launch_bounds__(256)
void cast_kernel(const float* __restrict__ in, bf16_t* __restrict__ out, size_t n) {
  size_t i = ((size_t)blockIdx.x * 256 + threadIdx.x) * 8;
  if (i + 8 > n) return;
  float4 a = *(const float4*)(in + i);
  float4 b = *(const float4*)(in + i + 4);
  bf16x8 o;
  o[0]=(bf16_t)a.x; o[1]=(bf16_t)a.y; o[2]=(bf16_t)a.z; o[3]=(bf16_t)a.w;
  o[4]=(bf16_t)b.x; o[5]=(bf16_t)b.y; o[6]=(bf16_t)b.z; o[7]=(bf16_t)b.w;
  *(bf16x8*)(out + i) = o;
}

// in: R x C f32 row-major -> out: outRows x R bf16 (out[c][r] = in[r][c], zero pad c>=C)
__global__ __launch_bounds__(256)
void transpose_cast_kernel(const float* __restrict__ in, bf16_t* __restrict__ out,
                           int R, int C, int outRows) {
  __shared__ float tile[32][33];
  const int c0 = blockIdx.x * 32;
  const int r0 = blockIdx.y * 32;
  const int tx = threadIdx.x & 31;
  const int ty = threadIdx.x >> 5;   // 0..7
#pragma unroll
  for (int k = 0; k < 4; ++k) {
    int r = r0 + ty + k*8;
    int c = c0 + tx;
    tile[ty + k*8][tx] = (c < C) ? in[(size_t)r * C + c] : 0.f;
  }
  __syncthreads();
#pragma unroll
  for (int k = 0; k < 4; ++k) {
    int oc = c0 + ty + k*8;
    int orr = r0 + tx;
    out[(size_t)oc * R + orr] = (bf16_t)tile[tx][ty + k*8];
  }
}

// ---------------- main GEMM: A(MxK bf16) @ B(NxK bf16, i.e. B^T) -> C(MxN OutT) ----------------
template <typename OutT>
__global__ __launch_bounds__(256, 2)
void gemm_bf16_tn(const bf16_t* __restrict__ A, const bf16_t* __restrict__ B,
                  OutT* __restrict__ C, int M, int N, int K) {
  __shared__ bf16_t sA[4096];   // fragment-order [mt(8)][lane(64)][e(8)]
  __shared__ bf16_t sB[4096];
  const int tid = threadIdx.x;
  const int lane = tid & 63;
  const int w = tid >> 6;
  const int wr = w >> 1, wc = w & 1;
  const long bm = (long)blockIdx.y * 128;
  const long bn = (long)blockIdx.x * 128;

  const int r0 = tid >> 1;            // row 0..127
  const int q0 = (tid & 1) * 2;       // k-chunk 0 or 2 (owns q0, q0+1)
  const int lds0 = ((r0 >> 4) * 64 + q0 * 16 + (r0 & 15)) * 8;
  const int lds1 = lds0 + 128;

  const bf16_t* Ag = A + (bm + r0) * (long)K + q0 * 8;
  const bf16_t* Bg = B + (bn + r0) * (long)K + q0 * 8;

  f32x4 acc[4][4] = {};

  for (int kt = 0; kt < K; kt += 32) {
    bf16x8 a0 = *(const bf16x8*)(Ag + kt);
    bf16x8 a1 = *(const bf16x8*)(Ag + kt + 8);
    bf16x8 b0 = *(const bf16x8*)(Bg + kt);
    bf16x8 b1 = *(const bf16x8*)(Bg + kt + 8);
    __syncthreads();
    *(bf16x8*)&sA[lds0] = a0;
    *(bf16x8*)&sA[lds1] = a1;
    *(bf16x8*)&sB[lds0] = b0;
    *(bf16x8*)&sB[lds1] = b1;
    __syncthreads();
    bf16x8 aF[4], bF[4];
#pragma unroll
    for (int i = 0; i < 4; ++i) aF[i] = *(const bf16x8*)&sA[((wr*4 + i)*64 + lane)*8];
#pragma unroll
    for (int i = 0; i < 4; ++i) bF[i] = *(const bf16x8*)&sB[((wc*4 + i)*64 + lane)*8];
#pragma unroll
    for (int mi = 0; mi < 4; ++mi)
#pragma unroll
      for (int ni = 0; ni < 4; ++ni)
        acc[mi][ni] = __builtin_amdgcn_mfma_f32_16x16x32_bf16(aF[mi], bF[ni], acc[mi][ni], 0, 0, 0);
  }

  const int cr = (lane >> 4) * 4;
  const int cc = lane & 15;
#pragma unroll
  for (int mi = 0; mi < 4; ++mi) {
#pragma unroll
    for (int ni = 0; ni < 4; ++ni) {
      long row = bm + wr*64 + mi*16 + cr;
      long col = bn + wc*64 + ni*16 + cc;
      OutT* Cp = C + row * (long)N + col;
#pragma unroll
      for (int r = 0; r < 4; ++r) Cp[(long)r * N] = (OutT)acc[mi][ni][r];
    }
  }
}

// ---------------- exact-f32 dt columns: hidden(8192x2048) @ W_in[:,8448:8512] ----------------
__global__ __launch_bounds__(256)
void dt_gemm_kernel(const float* __restrict__ X, const float* __restrict__ Win,
                    float* __restrict__ dtraw) {
  const int tid = threadIdx.x;
  const int h = tid & 63;
  const int tok = blockIdx.x * 4 + (tid >> 6);
  const float* xrow = X + (long)tok * DMODEL;
  const float* wp = Win + 8448 + h;
  float a0=0.f, a1=0.f, a2=0.f, a3=0.f;
  for (int k = 0; k < DMODEL; k += 4) {
    float4 xv = *(const float4*)(xrow + k);
    a0 += xv.x * wp[(long)(k+0)*8512];
    a1 += xv.y * wp[(long)(k+1)*8512];
    a2 += xv.z * wp[(long)(k+2)*8512];
    a3 += xv.w * wp[(long)(k+3)*8512];
  }
  dtraw[(long)tok*64 + h] = (a0+a1)+(a2+a3);
}

// ---------------- causal conv1d (K=4) + SiLU, split x/B/C ----------------
__global__ __launch_bounds__(256)
void conv_kernel(const bf16_t* __restrict__ xbc, const float* __restrict__ cw,
                 const float* __restrict__ cb, bf16_t* __restrict__ xo,
                 bf16_t* __restrict__ Bout, bf16_t* __restrict__ Cout) {
  const int c = blockIdx.x * 256 + threadIdx.x;   // 0..4351
  const int t0 = blockIdx.y * 8;
  const int bstart = (t0 >> 12) << 12;            // batch start token
  const float w0 = cw[c*4+0], w1 = cw[c*4+1], w2 = cw[c*4+2], w3 = cw[c*4+3];
  const float bias = cb[c];
  float in[11];
#pragma unroll
  for (int k = 0; k < 11; ++k) {
    int t = t0 - 3 + k;
    in[k] = (t >= bstart) ? (float)xbc[(size_t)t * XBCN + c] : 0.f;
  }
#pragma unroll
  for (int i = 0; i < 8; ++i) {
    float v = bias + w0*in[i] + w1*in[i+1] + w2*in[i+2] + w3*in[i+3];
    float s = v / (1.f + __expf(-v));
    int t = t0 + i;
    bf16_t o = (bf16_t)s;
    if (c < DINNER)           xo[(size_t)t * DINNER + c] = o;
    else if (c < DINNER+128)  Bout[(size_t)t * DSTATE + (c - DINNER)] = o;
    else                      Cout[(size_t)t * DSTATE + (c - DINNER - 128)] = o;
  }
}

// ---------------- softplus(dt)+cumsum(dA) per (b,chunk,head) ----------------
__global__ __launch_bounds__(256)
void dt_scan_kernel(const float* __restrict__ dtraw, const float* __restrict__ dt_bias,
                    const float* __restrict__ Avec, float* __restrict__ dt_s,
                    float* __restrict__ dAcs, float* __restrict__ cdec) {
  const int wid = blockIdx.x * 4 + (threadIdx.x >> 6);   // bc*64+h
  const int lane = threadIdx.x & 63;
  const int h = wid & 63;
  const int bc = wid >> 6;
  const long tok0 = (long)bc * 128;
  const float Ah = Avec[h];
  const float bias = dt_bias[h];
  float v0 = dtraw[(tok0 + lane)*64 + h] + bias;
  float v1 = dtraw[(tok0 + 64 + lane)*64 + h] + bias;
  float d0 = (v0 > 20.f) ? v0 : log1pf(expf(v0));
  float d1 = (v1 > 20.f) ? v1 : log1pf(expf(v1));
  float s0 = d0 * Ah;
  float s1 = d1 * Ah;
#pragma unroll
  for (int off = 1; off < 64; off <<= 1) {
    float t = __shfl_up(s0, off);
    if (lane >= off) s0 += t;
  }
  float tot0 = __shfl(s0, 63);
#pragma unroll
  for (int off = 1; off < 64; off <<= 1) {
    float t = __shfl_up(s1, off);
    if (lane >= off) s1 += t;
  }
  s1 += tot0;
  const size_t base = (size_t)wid * 128;
  dt_s[base + lane] = d0;
  dt_s[base + 64 + lane] = d1;
  dAcs[base + lane] = s0;
  dAcs[base + 64 + lane] = s1;
  if (lane == 63) cdec[wid] = __expf(s1);
}

// ---------------- per-chunk states: dtx^T @ (decay .* Bm) -> (64 x 128) bf16 ----------------
__global__ __launch_bounds__(256)
void states_kernel(const bf16_t* __restrict__ x, const bf16_t* __restrict__ Bm,
                   const float* __restrict__ dt_s, const float* __restrict__ dAcs,
                   bf16_t* __restrict__ states) {
  __shared__ bf16_t sDtx[8192];    // A-op (M=p, K=j) [kt(4)][mt(4)][lane][e]
  __shared__ bf16_t sBd[16384];    // B-op (N=n, K=j) [kt(4)][nt(8)][lane][e]
  __shared__ float sDt[128];
  __shared__ float sDec[128];
  const int wid = blockIdx.x;
  const int h = wid & 63;
  const int bc = wid >> 6;
  const int tid = threadIdx.x;
  const int lane = tid & 63;
  const int w = tid >> 6;
  const long tok0 = (long)bc * 128;
  const size_t dbase = (size_t)wid * 128;

  if (tid < 128) {
    sDt[tid] = dt_s[dbase + tid];
  } else {
    int j = tid - 128;
    sDec[j] = __expf(dAcs[dbase + 127] - dAcs[dbase + j]);
  }
  __syncthreads();

  {
    const int jj0 = tid >> 3;
    const int pg = (tid & 7) * 8;
#pragma unroll
    for (int t = 0; t < 4; ++t) {
      int j = t*32 + jj0;
      bf16x8 xv = *(const bf16x8*)&x[(tok0 + j)*(long)DINNER + h*64 + pg];
      float dtj = sDt[j];
      int kq = (j >> 5) * 4;
      int qe = ((j >> 3) & 3) * 16;
      int e = j & 7;
#pragma unroll
      for (int i = 0; i < 8; ++i) {
        int p = pg + i;
        sDtx[((kq + (p>>4))*64 + qe + (p&15))*8 + e] = (bf16_t)((float)xv[i]*dtj);
      }
    }
    const int jj1 = tid >> 4;
    const int ng = (tid & 15) * 8;
#pragma unroll
    for (int t = 0; t < 8; ++t) {
      int j = t*16 + jj1;
      bf16x8 bv = *(const bf16x8*)&Bm[(tok0 + j)*(long)DSTATE + ng];
      float dec = sDec[j];
      int kq = (j >> 5) * 8;
      int qe = ((j >> 3) & 3) * 16;
      int e = j & 7;
#pragma unroll
      for (int i = 0; i < 8; ++i) {
        int n = ng + i;
        sBd[((kq + (n>>4))*64 + qe + (n&15))*8 + e] = (bf16_t)((float)bv[i]*dec);
      }
    }
  }
  __syncthreads();

  f32x4 acc[4][2] = {};
#pragma unroll
  for (int kt = 0; kt < 4; ++kt) {
    bf16x8 aF[4], bF[2];
#pragma unroll
    for (int mt = 0; mt < 4; ++mt) aF[mt] = *(const bf16x8*)&sDtx[((kt*4 + mt)*64 + lane)*8];
#pragma unroll
    for (int nt = 0; nt < 2; ++nt) bF[nt] = *(const bf16x8*)&sBd[((kt*8 + w*2 + nt)*64 + lane)*8];
#pragma unroll
    for (int mt = 0; mt < 4; ++mt)
#pragma unroll
      for (int nt = 0; nt < 2; ++nt)
        acc[mt][nt] = __builtin_amdgcn_mfma_f32_16x16x32_bf16(aF[mt], bF[nt], acc[mt][nt], 0,0,0);
  }

  bf16_t* S = states + (size_t)wid * (HD * DSTATE);
  const int cr = (lane >> 4) * 4;
  const int cc = lane & 15;
#pragma unroll
  for (int mt = 0; mt < 4; ++mt)
#pragma unroll
    for (int nt = 0; nt < 2; ++nt) {
      int n = (w*2 + nt)*16 + cc;
#pragma unroll
      for (int r = 0; r < 4; ++r) {
        int p = mt*16 + cr + r;
        S[(size_t)p*DSTATE + n] = (bf16_t)acc[mt][nt][r];
      }
    }
}

// ---------------- inter-chunk scan over 32 chunks (in-place: states -> prevs) ----------------
__global__ __launch_bounds__(256)
void scan_kernel(bf16_t* __restrict__ sp, const float* __restrict__ cdec) {
  const size_t gid = (size_t)blockIdx.x * 256 + threadIdx.x;  // (b,h,p,n)
  const int n = gid & 127;
  const int p = (gid >> 7) & 63;
  const int h = (gid >> 13) & 63;
  const int b = (int)(gid >> 19);
  float prev = 0.f;
  const size_t pn = (size_t)p * 128 + n;
  for (int c = 0; c < 32; ++c) {
    const int wid = (b*32 + c)*64 + h;
    const size_t idx = (size_t)wid * 8192 + pn;
    float s = (float)sp[idx];
    sp[idx] = (bf16_t)prev;
    prev = cdec[wid] * prev + s;
  }
}

// ---------------- per-chunk Y: inter + intra + D*x (y written in-place over x) ----------------
__global__ __launch_bounds__(256)
void ssd_y_kernel(bf16_t* __restrict__ xy, const bf16_t* __restrict__ Bm,
                  const bf16_t* __restrict__ Cm, const bf16_t* __restrict__ prevs,
                  const float* __restrict__ dt_s, const float* __restrict__ dAcs,
                  const float* __restrict__ Dvec) {
  __shared__ bf16_t sG[16384];    // G as A-op (M=i, K=j) [kt(4)][mt(8)][lane][e]
  __shared__ bf16_t sDtx[8192];   // B-op (N=p, K=j) [kt(4)][nt(4)][lane][e]
  __shared__ float sDA[128];
  __shared__ float sEA[128];
  __shared__ float sDt[128];

  const int wid = blockIdx.x;
  const int h = wid & 63;
  const int bc = wid >> 6;
  const int tid = threadIdx.x;
  const int lane = tid & 63;
  const int w = tid >> 6;
  const long tok0 = (long)bc * 128;
  const size_t dbase = (size_t)wid * 128;

  if (tid < 128) {
    float v = dAcs[dbase + tid];
    sDA[tid] = v;
    sEA[tid] = __expf(v);
  } else {
    sDt[tid - 128] = dt_s[dbase + tid - 128];
  }
  __syncthreads();

  // stage dtx into LDS (B-op: N=p, K=j)
  {
    const int jj0 = tid >> 3;
    const int pg = (tid & 7) * 8;
#pragma unroll
    for (int t = 0; t < 4; ++t) {
      int j = t*32 + jj0;
      bf16x8 xv = *(const bf16x8*)&xy[(tok0 + j)*(long)DINNER + h*64 + pg];
      float dtj = sDt[j];
      int kq = (j >> 5) * 4;
      int qe = ((j >> 3) & 3) * 16;
      int e = j & 7;
#pragma unroll
      for (int i = 0; i < 8; ++i) {
        int p = pg + i;
        sDtx[((kq + (p>>4))*64 + qe + (p&15))*8 + e] = (bf16_t)((float)xv[i]*dtj);
      }
    }
  }

  // Cm A-op fragments direct from global (rows contiguous in n): regs, reused twice
  const int arow = (w*2)*16 + (lane & 15);
  const int koff = (lane >> 4) * 8;
  bf16x8 aCm[2][4];
#pragma unroll
  for (int mi = 0; mi < 2; ++mi)
#pragma unroll
    for (int kt = 0; kt < 4; ++kt)
      aCm[mi][kt] = *(const bf16x8*)&Cm[(tok0 + arow + mi*16)*(long)DSTATE + kt*32 + koff];

  // inter: Y2 = Cm @ prev^T (prev fragments direct from global)
  const bf16_t* P = prevs + (size_t)wid * 8192;
  f32x4 accY[2][4] = {};
#pragma unroll
  for (int kt = 0; kt < 4; ++kt) {
    bf16x8 bP[4];
#pragma unroll
    for (int ni = 0; ni < 4; ++ni)
      bP[ni] = *(const bf16x8*)&P[(size_t)(ni*16 + (lane & 15))*DSTATE + kt*32 + koff];
#pragma unroll
    for (int mi = 0; mi < 2; ++mi)
#pragma unroll
      for (int ni = 0; ni < 4; ++ni)
        accY[mi][ni] = __builtin_amdgcn_mfma_f32_16x16x32_bf16(aCm[mi][kt], bP[ni], accY[mi][ni], 0,0,0);
  }
  const int cr = (lane >> 4) * 4;
  const int cc = lane & 15;
#pragma unroll
  for (int mi = 0; mi < 2; ++mi)
#pragma unroll
    for (int r = 0; r < 4; ++r) {
      float e = sEA[(w*2 + mi)*16 + cr + r];
#pragma unroll
      for (int ni = 0; ni < 4; ++ni) accY[mi][ni][r] *= e;
    }

  // CB = Cm @ Bm^T (Bm fragments direct from global)
  f32x4 accS[2][8] = {};
#pragma unroll
  for (int kt = 0; kt < 4; ++kt) {
    bf16x8 bB[8];
#pragma unroll
    for (int nt = 0; nt < 8; ++nt)
      bB[nt] = *(const bf16x8*)&Bm[(tok0 + nt*16 + (lane & 15))*(long)DSTATE + kt*32 + koff];
#pragma unroll
    for (int mi = 0; mi < 2; ++mi)
#pragma unroll
      for (int nt = 0; nt < 8; ++nt)
        accS[mi][nt] = __builtin_amdgcn_mfma_f32_16x16x32_bf16(aCm[mi][kt], bB[nt], accS[mi][nt], 0,0,0);
  }

  // G = tril .* CB .* exp(dA_i - dA_j), stored to LDS as A-op (M=i, K=j)
#pragma unroll
  for (int mi = 0; mi < 2; ++mi)
#pragma unroll
    for (int nt = 0; nt < 8; ++nt)
#pragma unroll
      for (int r = 0; r < 4; ++r) {
        int i = (w*2 + mi)*16 + cr + r;
        int j = nt*16 + cc;
        float g = (i >= j) ? accS[mi][nt][r] * __expf(sDA[i] - sDA[j]) : 0.f;
        sG[(((j>>5)*8 + (i>>4))*64 + ((j>>3)&3)*16 + (i&15))*8 + (j&7)] = (bf16_t)g;
      }
  __syncthreads();   // dtx staged + G complete

  // intra: Y += G @ dtx^T
#pragma unroll
  for (int kt = 0; kt < 4; ++kt) {
    bf16x8 aG[2], bD[4];
#pragma unroll
    for (int mi = 0; mi < 2; ++mi) aG[mi] = *(const bf16x8*)&sG[((kt*8 + w*2 + mi)*64 + lane)*8];
#pragma unroll
    for (int ni = 0; ni < 4; ++ni) bD[ni] = *(const bf16x8*)&sDtx[((kt*4 + ni)*64 + lane)*8];
#pragma unroll
    for (int mi = 0; mi < 2; ++mi)
#pragma unroll
      for (int ni = 0; ni < 4; ++ni)
        accY[mi][ni] = __builtin_amdgcn_mfma_f32_16x16x32_bf16(aG[mi], bD[ni], accY[mi][ni], 0,0,0);
  }

  const float Dh = Dvec[h];
#pragma unroll
  for (int mi = 0; mi < 2; ++mi)
#pragma unroll
    for (int ni = 0; ni < 4; ++ni)
#pragma unroll
      for (int r = 0; r < 4; ++r) {
        long tokr = tok0 + (w*2 + mi)*16 + cr + r;
        int p = ni*16 + cc;
        long idx = tokr * DINNER + h*64 + p;
        float xv = (float)xy[idx];
        xy[idx] = (bf16_t)(accY[mi][ni][r] + Dh * xv);
      }
}

// ---------------- gating + RMS norm ----------------
__global__ __launch_bounds__(256)
void gate_kernel(const bf16_t* __restrict__ y, const bf16_t* __restrict__ z,
                 const float* __restrict__ norm_w, bf16_t* __restrict__ yn) {
  const int tok = blockIdx.x;
  const int tid = threadIdx.x;
  const int lane = tid & 63;
  const int w = tid >> 6;
  const bf16_t* yrow = y + (size_t)tok * DINNER;
  const bf16_t* zrow = z + (size_t)tok * DINNER;
  float local[16];
  float ss = 0.f;
#pragma unroll
  for (int v = 0; v < 2; ++v) {
    int col = tid*16 + v*8;
    bf16x8 yv = *(const bf16x8*)&yrow[col];
    bf16x8 zv = *(const bf16x8*)&zrow[col];
#pragma unroll
    for (int i = 0; i < 8; ++i) {
      float zf = (float)zv[i];
      float g = zf / (1.f + __expf(-zf));
      float t = (float)yv[i] * g;
      local[v*8 + i] = t;
      ss += t*t;
    }
  }
#pragma unroll
  for (int off = 32; off > 0; off >>= 1) ss += __shfl_xor(ss, off);
  __shared__ float red[4];
  if (lane == 0) red[w] = ss;
  __syncthreads();
  float rms = rsqrtf((red[0]+red[1]+red[2]+red[3]) * (1.f/DINNER) + 1e-5f);
  bf16_t* orow = yn + (size_t)tok * DINNER;
#pragma unroll
  for (int v = 0; v < 2; ++v) {
    int col = tid*16 + v*8;
    bf16x8 o;
#pragma unroll
    for (int i = 0; i < 8; ++i) o[i] = (bf16_t)(local[v*8+i] * rms * norm_w[col+i]);
    *(bf16x8*)&orow[col] = o;
  }
}

// ---------------- launch ----------------
extern "C" void kernel_launch(void* const* d_in, const int* in_sizes, int n_in,
                              void* d_out, int out_size, void* d_ws, size_t ws_size,
                              hipStream_t stream) {
  const float* hidden  = (const float*)d_in[0];
  const float* W_in    = (const float*)d_in[1];
  const float* conv_w  = (const float*)d_in[2];
  const float* conv_b  = (const float*)d_in[3];
  const float* Avec    = (const float*)d_in[4];
  const float* Dvec    = (const float*)d_in[5];
  const float* dt_bias = (const float*)d_in[6];
  const float* norm_w  = (const float*)d_in[7];
  const float* W_out   = (const float*)d_in[8];

  char* ws = (char*)d_ws;
  size_t off = 0;
  auto take = [&](size_t bytes) -> char* {
    char* p = ws + off;
    off += (bytes + 255) & ~(size_t)255;
    return p;
  };
  // R1 (64MB) time-shared: Xb (phase 1) -> states/prevs (phase 2) -> ynbuf (phase 3)
  bf16_t* R1    = (bf16_t*)take((size_t)NBC * NH * HD * DSTATE * 2);
  bf16_t* WinT  = (bf16_t*)take((size_t)WINT_ROWS * DMODEL * 2);   // later reused as WoutT
  bf16_t* xbc   = (bf16_t*)take((size_t)TOK * XBCN * 2);
  bf16_t* xconv = (bf16_t*)take((size_t)TOK * DINNER * 2);         // y written in-place
  bf16_t* Bmat  = (bf16_t*)take((size_t)TOK * DSTATE * 2);
  bf16_t* Cmat  = (bf16_t*)take((size_t)TOK * DSTATE * 2);
  float*  dtraw = (float*)take((size_t)TOK * NH * 4);
  float*  dt_s  = (float*)take((size_t)TOK * NH * 4);
  float*  dAcs  = (float*)take((size_t)TOK * NH * 4);
  float*  cdec  = (float*)take((size_t)NBC * NH * 4);
  if (off > ws_size) return;   // ~242 MB required

  bf16_t* Xb      = R1;
  bf16_t* statesB = R1;
  bf16_t* ynbuf   = R1;
  bf16_t* WoutT   = WinT;
  bf16_t* zbuf    = (bf16_t*)d_out;   // z stored as bf16 in d_out (exactly 64MB)
  float*  out     = (float*)d_out;

  cast_kernel<<<(TOK*DMODEL)/2048, 256, 0, stream>>>(hidden, Xb, (size_t)TOK*DMODEL);
  transpose_cast_kernel<<<dim3(WINT_ROWS/32, DMODEL/32), 256, 0, stream>>>(W_in, WinT, DMODEL, 8512, WINT_ROWS);
  dt_gemm_kernel<<<TOK/4, 256, 0, stream>>>(hidden, W_in, dtraw);
  // z-gemm -> d_out (bf16), xbc-gemm -> xbc
  gemm_bf16_tn<bf16_t><<<dim3(DINNER/128, TOK/128), 256, 0, stream>>>(Xb, WinT, zbuf, TOK, DINNER, DMODEL);
  gemm_bf16_tn<bf16_t><<<dim3(XBCN/128, TOK/128), 256, 0, stream>>>(Xb, WinT + (size_t)DINNER*DMODEL, xbc, TOK, XBCN, DMODEL);
  // WinT dead now; transpose W_out into its space
  transpose_cast_kernel<<<dim3(DMODEL/32, DINNER/32), 256, 0, stream>>>(W_out, WoutT, DINNER, DMODEL, DMODEL);
  conv_kernel<<<dim3(XBCN/256, TOK/8), 256, 0, stream>>>(xbc, conv_w, conv_b, xconv, Bmat, Cmat);
  dt_scan_kernel<<<(NBC*NH)/4, 256, 0, stream>>>(dtraw, dt_bias, Avec, dt_s, dAcs, cdec);
  states_kernel<<<NBC*NH, 256, 0, stream>>>(xconv, Bmat, dt_s, dAcs, statesB);
  scan_kernel<<<(NBC*NH*HD*DSTATE)/(32*256), 256, 0, stream>>>(statesB, cdec);
  ssd_y_kernel<<<NBC*NH, 256, 0, stream>>>(xconv, Bmat, Cmat, statesB, dt_s, dAcs, Dvec);
  gate_kernel<<<TOK, 256, 0, stream>>>(xconv, zbuf, norm_w, ynbuf);
  gemm_bf16_tn<float><<<dim3(DMODEL/128, TOK/128), 256, 0, stream>>>(ynbuf, WoutT, out, TOK, DMODEL, DINNER);
}